// Round 5
// baseline (384.409 us; speedup 1.0000x reference)
//
#include <hip/hip_runtime.h>
#include <hip/hip_bf16.h>

#define NN 100000   // nodes
#define FF 10       // input features
#define HH 20       // hidden dim
#define GG 512      // graphs
#define LL 2        // labels

#define NB 500      // dst buckets
#define BNODES 200  // nodes per bucket (NN / NB)
#define TILE 4096   // edges per block in multisplit
#define SRC_BITS 17
#define SRC_MASK 0x1FFFFu

// bf16 helpers (storage-only; all math in f32)
__device__ inline unsigned short f2bf(float f) {
  unsigned u = __float_as_uint(f);
  unsigned r = u + 0x7FFFu + ((u >> 16) & 1u);
  return (unsigned short)(r >> 16);
}
__device__ inline float bflo(unsigned u) { return __uint_as_float(u << 16); }
__device__ inline float bfhi(unsigned u) { return __uint_as_float(u & 0xFFFF0000u); }

// ---------------------------------------------------------------------------
// Cast x f32->bf16 and zero all small accumulators (folded memsets).
// ---------------------------------------------------------------------------
__global__ __launch_bounds__(256) void cast_init_kernel(
    const float* __restrict__ x, unsigned short* __restrict__ xb,
    float* __restrict__ sump, int* __restrict__ maxp, float* __restrict__ cnt,
    int* __restrict__ bcnt, int n) {
  int i = blockIdx.x * 256 + threadIdx.x;
  if (i < n) xb[i] = f2bf(x[i]);
  if (i < GG * HH) {
    sump[i] = 0.0f;
    maxp[i] = 0;
  }
  if (i < GG) cnt[i] = 0.0f;
  if (i < NB) bcnt[i] = 0;
}

// ---------------------------------------------------------------------------
// K0: per-bucket edge counts (LDS histogram, then merge).
// ---------------------------------------------------------------------------
__global__ __launch_bounds__(256) void bucket_count_kernel(
    const int* __restrict__ dst, int* __restrict__ bcnt, int E) {
  __shared__ int lh[NB];
  for (int i = threadIdx.x; i < NB; i += 256) lh[i] = 0;
  __syncthreads();
  int base = blockIdx.x * TILE;
  for (int i = threadIdx.x; i < TILE; i += 256) {
    int e = base + i;
    if (e < E) atomicAdd(&lh[dst[e] / BNODES], 1);
  }
  __syncthreads();
  for (int i = threadIdx.x; i < NB; i += 256) {
    int c = lh[i];
    if (c) atomicAdd(&bcnt[i], c);
  }
}

// ---------------------------------------------------------------------------
// K1: scan bucket counts -> gofs[NB+1], init cursor. 256 thr, 2 elems each.
// ---------------------------------------------------------------------------
__global__ __launch_bounds__(256) void bucket_scan_kernel(
    const int* __restrict__ bcnt, int* __restrict__ gofs,
    int* __restrict__ cursor) {
  __shared__ int ss[512];
  int t = threadIdx.x;
  int own0 = (t < NB) ? bcnt[t] : 0;
  int own1 = (t + 256 < NB) ? bcnt[t + 256] : 0;
  ss[t] = own0;
  ss[t + 256] = own1;
  __syncthreads();
  for (int off = 1; off < 512; off <<= 1) {
    int a0 = (t >= off) ? ss[t - off] : 0;
    int a1 = (t + 256 >= off) ? ss[t + 256 - off] : 0;
    __syncthreads();
    ss[t] += a0;
    ss[t + 256] += a1;
    __syncthreads();
  }
  if (t < NB) {
    int ex = ss[t] - own0;
    gofs[t] = ex;
    cursor[t] = ex;
  }
  int i1 = t + 256;
  if (i1 < NB) {
    int ex = ss[i1] - own1;
    gofs[i1] = ex;
    cursor[i1] = ex;
  }
  if (t == 0) gofs[NB] = ss[NB - 1];
}

// ---------------------------------------------------------------------------
// K2: slim multisplit. Phase 1: LDS histogram of this tile; reserve global
// per-bucket ranges. Phase 2: re-read tile (L2-hot) and write payloads
// directly into block-owned runs (scattered 4B stores absorbed by L2 since
// each run is contiguous and single-block-owned).
// Payload pack: (local_dst << 17) | src.
// ---------------------------------------------------------------------------
__global__ __launch_bounds__(256) void multisplit_kernel(
    const int* __restrict__ src, const int* __restrict__ dst,
    int* __restrict__ cursor, unsigned int* __restrict__ pay, int E) {
  __shared__ int lhist[NB];
  __shared__ int gbase[NB];
  __shared__ int lcur[NB];
  int t = threadIdx.x;
  for (int i = t; i < NB; i += 256) lhist[i] = 0;
  __syncthreads();

  int base = blockIdx.x * TILE;
  for (int i = t; i < TILE; i += 256) {
    int e = base + i;
    if (e < E) atomicAdd(&lhist[dst[e] / BNODES], 1);
  }
  __syncthreads();

  for (int i = t; i < NB; i += 256) {
    int c = lhist[i];
    gbase[i] = c ? atomicAdd(&cursor[i], c) : 0;
    lcur[i] = 0;
  }
  __syncthreads();

  for (int i = t; i < TILE; i += 256) {
    int e = base + i;
    if (e < E) {
      int d = dst[e];
      int s = src[e];
      int bk = d / BNODES;
      int ld = d - bk * BNODES;
      int r = atomicAdd(&lcur[bk], 1);
      pay[gbase[bk] + r] = ((unsigned)ld << SRC_BITS) | (unsigned)s;
    }
  }
}

// ---------------------------------------------------------------------------
// K3: per-bucket CSR finalize. One block owns a 200-node bucket; all
// scattered writes confined to the block-owned [k0,k1) range.
// ---------------------------------------------------------------------------
__global__ __launch_bounds__(256) void bucket_csr_kernel(
    const unsigned int* __restrict__ pay, const int* __restrict__ gofs,
    int* __restrict__ srt, int* __restrict__ rofs, int* __restrict__ rend) {
  __shared__ int lhist[BNODES];
  __shared__ int lofs[BNODES];
  __shared__ int lcur[BNODES];
  __shared__ int ss[256];
  int b = blockIdx.x;
  int t = threadIdx.x;
  int k0 = gofs[b], k1 = gofs[b + 1];

  if (t < BNODES) lhist[t] = 0;
  __syncthreads();
  for (int k = k0 + t; k < k1; k += 256)
    atomicAdd(&lhist[pay[k] >> SRC_BITS], 1);
  __syncthreads();

  int own = (t < BNODES) ? lhist[t] : 0;
  ss[t] = own;
  __syncthreads();
  for (int off = 1; off < 256; off <<= 1) {
    int a0 = (t >= off) ? ss[t - off] : 0;
    __syncthreads();
    ss[t] += a0;
    __syncthreads();
  }
  if (t < BNODES) {
    int ex = ss[t] - own;
    lofs[t] = ex;
    lcur[t] = 0;
    rofs[b * BNODES + t] = k0 + ex;
    rend[b * BNODES + t] = k0 + ex + own;
  }
  __syncthreads();

  for (int k = k0 + t; k < k1; k += 256) {
    unsigned int p = pay[k];
    int ld = p >> SRC_BITS;
    int s = (int)(p & SRC_MASK);
    int r = atomicAdd(&lcur[ld], 1);
    srt[k0 + lofs[ld] + r] = s;
  }
}

// ---------------------------------------------------------------------------
// Fused layer (layers 1,2): thread per node. Gather bf16 rows with f32
// register accumulation (2x edge unroll), then dense + bias + root + ReLU,
// output bf16. Weights broadcast from LDS.
// ---------------------------------------------------------------------------
template<int DIN>
__global__ __launch_bounds__(256) void layer_fused_kernel(
    const unsigned short* __restrict__ xin, const int* __restrict__ rofs,
    const int* __restrict__ rend, const int* __restrict__ srt,
    const float* __restrict__ Wrel, const float* __restrict__ bb,
    const float* __restrict__ Wroot, unsigned short* __restrict__ out,
    int n_nodes) {
  __shared__ float sWrel[DIN * HH];
  __shared__ float sWroot[DIN * HH];
  __shared__ float sb[HH];
  int t = threadIdx.x;
  for (int i = t; i < DIN * HH; i += 256) {
    sWrel[i] = Wrel[i];
    sWroot[i] = Wroot[i];
  }
  if (t < HH) sb[t] = bb[t];
  __syncthreads();
  int n = blockIdx.x * 256 + t;
  if (n >= n_nodes) return;

  float acc[DIN];
#pragma unroll
  for (int f = 0; f < DIN; f++) acc[f] = 0.0f;

  int k0 = rofs[n], k1 = rend[n];
  int k = k0;
  if (DIN == 20) {
    for (; k + 1 < k1; k += 2) {
      int s0 = srt[k], s1 = srt[k + 1];
      const uint2* p0 = (const uint2*)(xin + (size_t)s0 * 20);
      const uint2* p1 = (const uint2*)(xin + (size_t)s1 * 20);
      uint2 a0 = p0[0], a1 = p0[1], a2 = p0[2], a3 = p0[3], a4 = p0[4];
      uint2 c0 = p1[0], c1 = p1[1], c2 = p1[2], c3 = p1[3], c4 = p1[4];
      acc[0] += bflo(a0.x) + bflo(c0.x);  acc[1] += bfhi(a0.x) + bfhi(c0.x);
      acc[2] += bflo(a0.y) + bflo(c0.y);  acc[3] += bfhi(a0.y) + bfhi(c0.y);
      acc[4] += bflo(a1.x) + bflo(c1.x);  acc[5] += bfhi(a1.x) + bfhi(c1.x);
      acc[6] += bflo(a1.y) + bflo(c1.y);  acc[7] += bfhi(a1.y) + bfhi(c1.y);
      acc[8] += bflo(a2.x) + bflo(c2.x);  acc[9] += bfhi(a2.x) + bfhi(c2.x);
      acc[10] += bflo(a2.y) + bflo(c2.y); acc[11] += bfhi(a2.y) + bfhi(c2.y);
      acc[12] += bflo(a3.x) + bflo(c3.x); acc[13] += bfhi(a3.x) + bfhi(c3.x);
      acc[14] += bflo(a3.y) + bflo(c3.y); acc[15] += bfhi(a3.y) + bfhi(c3.y);
      acc[16] += bflo(a4.x) + bflo(c4.x); acc[17] += bfhi(a4.x) + bfhi(c4.x);
      acc[18] += bflo(a4.y) + bflo(c4.y); acc[19] += bfhi(a4.y) + bfhi(c4.y);
    }
    for (; k < k1; k++) {
      int s = srt[k];
      const uint2* p = (const uint2*)(xin + (size_t)s * 20);
      uint2 a0 = p[0], a1 = p[1], a2 = p[2], a3 = p[3], a4 = p[4];
      acc[0] += bflo(a0.x);  acc[1] += bfhi(a0.x);
      acc[2] += bflo(a0.y);  acc[3] += bfhi(a0.y);
      acc[4] += bflo(a1.x);  acc[5] += bfhi(a1.x);
      acc[6] += bflo(a1.y);  acc[7] += bfhi(a1.y);
      acc[8] += bflo(a2.x);  acc[9] += bfhi(a2.x);
      acc[10] += bflo(a2.y); acc[11] += bfhi(a2.y);
      acc[12] += bflo(a3.x); acc[13] += bfhi(a3.x);
      acc[14] += bflo(a3.y); acc[15] += bfhi(a3.y);
      acc[16] += bflo(a4.x); acc[17] += bfhi(a4.x);
      acc[18] += bflo(a4.y); acc[19] += bfhi(a4.y);
    }
  } else {
    for (; k + 1 < k1; k += 2) {
      int s0 = srt[k], s1 = srt[k + 1];
      const unsigned* p0 = (const unsigned*)(xin + (size_t)s0 * 10);
      const unsigned* p1 = (const unsigned*)(xin + (size_t)s1 * 10);
      unsigned a0 = p0[0], a1 = p0[1], a2 = p0[2], a3 = p0[3], a4 = p0[4];
      unsigned c0 = p1[0], c1 = p1[1], c2 = p1[2], c3 = p1[3], c4 = p1[4];
      acc[0] += bflo(a0) + bflo(c0); acc[1] += bfhi(a0) + bfhi(c0);
      acc[2] += bflo(a1) + bflo(c1); acc[3] += bfhi(a1) + bfhi(c1);
      acc[4] += bflo(a2) + bflo(c2); acc[5] += bfhi(a2) + bfhi(c2);
      acc[6] += bflo(a3) + bflo(c3); acc[7] += bfhi(a3) + bfhi(c3);
      acc[8] += bflo(a4) + bflo(c4); acc[9] += bfhi(a4) + bfhi(c4);
    }
    for (; k < k1; k++) {
      int s = srt[k];
      const unsigned* p = (const unsigned*)(xin + (size_t)s * 10);
      unsigned a0 = p[0], a1 = p[1], a2 = p[2], a3 = p[3], a4 = p[4];
      acc[0] += bflo(a0); acc[1] += bfhi(a0);
      acc[2] += bflo(a1); acc[3] += bfhi(a1);
      acc[4] += bflo(a2); acc[5] += bfhi(a2);
      acc[6] += bflo(a3); acc[7] += bfhi(a3);
      acc[8] += bflo(a4); acc[9] += bfhi(a4);
    }
  }

  // root row
  float xr[DIN];
  if (DIN == 20) {
    const uint2* xp = (const uint2*)(xin + (size_t)n * 20);
#pragma unroll
    for (int c = 0; c < 5; c++) {
      uint2 u = xp[c];
      xr[4 * c + 0] = bflo(u.x); xr[4 * c + 1] = bfhi(u.x);
      xr[4 * c + 2] = bflo(u.y); xr[4 * c + 3] = bfhi(u.y);
    }
  } else {
    const unsigned* xp = (const unsigned*)(xin + (size_t)n * 10);
#pragma unroll
    for (int c = 0; c < 5; c++) {
      unsigned u = xp[c];
      xr[2 * c + 0] = bflo(u); xr[2 * c + 1] = bfhi(u);
    }
  }

  float o[HH];
#pragma unroll
  for (int j = 0; j < HH; j++) o[j] = sb[j];
#pragma unroll
  for (int f = 0; f < DIN; f++) {
    float a = acc[f], xv = xr[f];
#pragma unroll
    for (int j = 0; j < HH; j++)
      o[j] += a * sWrel[f * HH + j] + xv * sWroot[f * HH + j];
  }
  uint2* orow = (uint2*)(out + (size_t)n * HH);
#pragma unroll
  for (int c = 0; c < 5; c++) {
    unsigned lo = (unsigned)f2bf(fmaxf(o[4 * c + 0], 0.0f)) |
                  ((unsigned)f2bf(fmaxf(o[4 * c + 1], 0.0f)) << 16);
    unsigned hi = (unsigned)f2bf(fmaxf(o[4 * c + 2], 0.0f)) |
                  ((unsigned)f2bf(fmaxf(o[4 * c + 3], 0.0f)) << 16);
    orow[c] = make_uint2(lo, hi);
  }
}

// ---------------------------------------------------------------------------
// Layer 3 fused with pooling: gather + dense + relu + LDS per-graph partial
// pools, few global atomics. Post-ReLU >= 0 -> int atomicMax on float bits is
// order-correct; zero init gives where(cnt>0,max,0).
// ---------------------------------------------------------------------------
#define GMAX 8
__global__ __launch_bounds__(256) void layer_pool_kernel(
    const unsigned short* __restrict__ xin, const int* __restrict__ rofs,
    const int* __restrict__ rend, const int* __restrict__ srt,
    const float* __restrict__ Wrel, const float* __restrict__ bb,
    const float* __restrict__ Wroot, const int* __restrict__ batch,
    float* __restrict__ sump, int* __restrict__ maxp, float* __restrict__ cnt,
    int n_nodes) {
  __shared__ float sWrel[HH * HH];
  __shared__ float sWroot[HH * HH];
  __shared__ float sb[HH];
  __shared__ float gsum[GMAX * HH];
  __shared__ int gmax[GMAX * HH];
  __shared__ int gcnt[GMAX];
  __shared__ int g0s;
  int t = threadIdx.x;
  for (int i = t; i < HH * HH; i += 256) {
    sWrel[i] = Wrel[i];
    sWroot[i] = Wroot[i];
  }
  if (t < HH) sb[t] = bb[t];
  for (int i = t; i < GMAX * HH; i += 256) {
    gsum[i] = 0.0f;
    gmax[i] = 0;
  }
  if (t < GMAX) gcnt[t] = 0;
  if (t == 0) g0s = batch[blockIdx.x * 256];
  __syncthreads();

  int n = blockIdx.x * 256 + t;
  if (n < n_nodes) {
    float acc[HH];
#pragma unroll
    for (int f = 0; f < HH; f++) acc[f] = 0.0f;
    int k0 = rofs[n], k1 = rend[n];
    int k = k0;
    for (; k + 1 < k1; k += 2) {
      int s0 = srt[k], s1 = srt[k + 1];
      const uint2* p0 = (const uint2*)(xin + (size_t)s0 * 20);
      const uint2* p1 = (const uint2*)(xin + (size_t)s1 * 20);
      uint2 a0 = p0[0], a1 = p0[1], a2 = p0[2], a3 = p0[3], a4 = p0[4];
      uint2 c0 = p1[0], c1 = p1[1], c2 = p1[2], c3 = p1[3], c4 = p1[4];
      acc[0] += bflo(a0.x) + bflo(c0.x);  acc[1] += bfhi(a0.x) + bfhi(c0.x);
      acc[2] += bflo(a0.y) + bflo(c0.y);  acc[3] += bfhi(a0.y) + bfhi(c0.y);
      acc[4] += bflo(a1.x) + bflo(c1.x);  acc[5] += bfhi(a1.x) + bfhi(c1.x);
      acc[6] += bflo(a1.y) + bflo(c1.y);  acc[7] += bfhi(a1.y) + bfhi(c1.y);
      acc[8] += bflo(a2.x) + bflo(c2.x);  acc[9] += bfhi(a2.x) + bfhi(c2.x);
      acc[10] += bflo(a2.y) + bflo(c2.y); acc[11] += bfhi(a2.y) + bfhi(c2.y);
      acc[12] += bflo(a3.x) + bflo(c3.x); acc[13] += bfhi(a3.x) + bfhi(c3.x);
      acc[14] += bflo(a3.y) + bflo(c3.y); acc[15] += bfhi(a3.y) + bfhi(c3.y);
      acc[16] += bflo(a4.x) + bflo(c4.x); acc[17] += bfhi(a4.x) + bfhi(c4.x);
      acc[18] += bflo(a4.y) + bflo(c4.y); acc[19] += bfhi(a4.y) + bfhi(c4.y);
    }
    for (; k < k1; k++) {
      int s = srt[k];
      const uint2* p = (const uint2*)(xin + (size_t)s * 20);
      uint2 a0 = p[0], a1 = p[1], a2 = p[2], a3 = p[3], a4 = p[4];
      acc[0] += bflo(a0.x);  acc[1] += bfhi(a0.x);
      acc[2] += bflo(a0.y);  acc[3] += bfhi(a0.y);
      acc[4] += bflo(a1.x);  acc[5] += bfhi(a1.x);
      acc[6] += bflo(a1.y);  acc[7] += bfhi(a1.y);
      acc[8] += bflo(a2.x);  acc[9] += bfhi(a2.x);
      acc[10] += bflo(a2.y); acc[11] += bfhi(a2.y);
      acc[12] += bflo(a3.x); acc[13] += bfhi(a3.x);
      acc[14] += bflo(a3.y); acc[15] += bfhi(a3.y);
      acc[16] += bflo(a4.x); acc[17] += bfhi(a4.x);
      acc[18] += bflo(a4.y); acc[19] += bfhi(a4.y);
    }

    float xr[HH];
    const uint2* xp = (const uint2*)(xin + (size_t)n * 20);
#pragma unroll
    for (int c = 0; c < 5; c++) {
      uint2 u = xp[c];
      xr[4 * c + 0] = bflo(u.x); xr[4 * c + 1] = bfhi(u.x);
      xr[4 * c + 2] = bflo(u.y); xr[4 * c + 3] = bfhi(u.y);
    }
    float o[HH];
#pragma unroll
    for (int j = 0; j < HH; j++) o[j] = sb[j];
#pragma unroll
    for (int f = 0; f < HH; f++) {
      float a = acc[f], xv = xr[f];
#pragma unroll
      for (int j = 0; j < HH; j++)
        o[j] += a * sWrel[f * HH + j] + xv * sWroot[f * HH + j];
    }
#pragma unroll
    for (int j = 0; j < HH; j++) o[j] = fmaxf(o[j], 0.0f);

    int g = batch[n];
    int gl = g - g0s;
    if (gl >= 0 && gl < GMAX) {
      atomicAdd(&gcnt[gl], 1);
#pragma unroll
      for (int j = 0; j < HH; j++) {
        atomicAdd(&gsum[gl * HH + j], o[j]);
        atomicMax(&gmax[gl * HH + j], __float_as_int(o[j]));
      }
    } else {  // pathological fallback
      atomicAdd(&cnt[g], 1.0f);
#pragma unroll
      for (int j = 0; j < HH; j++) {
        atomicAdd(&sump[g * HH + j], o[j]);
        atomicMax(&maxp[g * HH + j], __float_as_int(o[j]));
      }
    }
  }
  __syncthreads();

  for (int i = t; i < GMAX * HH; i += 256) {
    int gl = i / HH;
    int g = g0s + gl;
    if (g < GG) {
      float sv = gsum[i];
      if (sv != 0.0f) atomicAdd(&sump[g * HH + (i - gl * HH)], sv);
      int mv = gmax[i];
      if (mv != 0) atomicMax(&maxp[g * HH + (i - gl * HH)], mv);
    }
  }
  if (t < GMAX) {
    int c = gcnt[t];
    int g = g0s + t;
    if (c && g < GG) atomicAdd(&cnt[g], (float)c);
  }
}

__global__ __launch_bounds__(256) void readout_kernel(
    const float* __restrict__ sump, const int* __restrict__ maxp,
    const float* __restrict__ cnt, const float* __restrict__ Wlin,
    const float* __restrict__ blin, float* __restrict__ out) {
  int idx = blockIdx.x * 256 + threadIdx.x;
  if (idx >= GG * LL) return;
  int g = idx / LL;
  int l = idx - g * LL;
  float c = cnt[g];
  float inv = 1.0f / fmaxf(c, 1.0f);
  float acc = blin[l];
#pragma unroll
  for (int j = 0; j < HH; j++) {
    float mx = __int_as_float(maxp[g * HH + j]);
    float mean = sump[g * HH + j] * inv;
    acc += mx * Wlin[j * LL + l];
    acc += mean * Wlin[(HH + j) * LL + l];
  }
  out[idx] = acc;
}

extern "C" void kernel_launch(void* const* d_in, const int* in_sizes, int n_in,
                              void* d_out, int out_size, void* d_ws,
                              size_t ws_size, hipStream_t stream) {
  const float* x = (const float*)d_in[0];
  const int* edge_index = (const int*)d_in[1];
  const int* batch = (const int*)d_in[2];
  const float* W_rel1 = (const float*)d_in[3];
  const float* b1 = (const float*)d_in[4];
  const float* W_root1 = (const float*)d_in[5];
  const float* W_rel2 = (const float*)d_in[6];
  const float* b2 = (const float*)d_in[7];
  const float* W_root2 = (const float*)d_in[8];
  const float* W_rel3 = (const float*)d_in[9];
  const float* b3 = (const float*)d_in[10];
  const float* W_root3 = (const float*)d_in[11];
  const float* W_lin = (const float*)d_in[12];
  const float* b_lin = (const float*)d_in[13];
  float* out = (float*)d_out;

  const int E = in_sizes[1] / 2;
  const int n_nodes = in_sizes[0] / FF;  // == NN
  const int* src = edge_index;
  const int* dst = edge_index + E;
  const int Epad = (E + 3) & ~3;  // keep 16B alignment of later chunks

  // Workspace layout (all chunk sizes multiples of 4 ints -> 16B aligned)
  unsigned int* pay = (unsigned int*)d_ws;       // Epad u32
  int* srt = (int*)(pay + Epad);                 // Epad
  int* rofs = srt + Epad;                        // NN
  int* rend = rofs + NN;                         // NN
  int* bcnt = rend + NN;                         // 512
  int* gofs = bcnt + 512;                        // 512 (NB+1 used)
  int* cursor = gofs + 512;                      // 512
  float* sump = (float*)(cursor + 512);          // GG*HH
  int* maxp = (int*)(sump + GG * HH);            // GG*HH
  float* cnt = (float*)(maxp + GG * HH);         // 512
  unsigned short* xb = (unsigned short*)(cnt + 512);  // NN*FF bf16 (2MB)
  unsigned short* h1 = xb + (size_t)NN * FF;     // NN*HH bf16 (4MB)
  unsigned short* h2 = h1 + (size_t)NN * HH;     // NN*HH bf16 (4MB)

  const int edge_tiles = (E + TILE - 1) / TILE;
  const int node_blocks = (n_nodes + 255) / 256;

  // ---- Cast x to bf16 + zero accumulators (folded) ----
  cast_init_kernel<<<(n_nodes * FF + 255) / 256, 256, 0, stream>>>(
      x, xb, sump, maxp, cnt, bcnt, n_nodes * FF);

  // ---- CSR build via slim bucketed multisplit ----
  bucket_count_kernel<<<edge_tiles, 256, 0, stream>>>(dst, bcnt, E);
  bucket_scan_kernel<<<1, 256, 0, stream>>>(bcnt, gofs, cursor);
  multisplit_kernel<<<edge_tiles, 256, 0, stream>>>(src, dst, cursor, pay, E);
  bucket_csr_kernel<<<NB, 256, 0, stream>>>(pay, gofs, srt, rofs, rend);

  // ---- Fused layers ----
  layer_fused_kernel<FF><<<node_blocks, 256, 0, stream>>>(
      xb, rofs, rend, srt, W_rel1, b1, W_root1, h1, n_nodes);
  layer_fused_kernel<HH><<<node_blocks, 256, 0, stream>>>(
      h1, rofs, rend, srt, W_rel2, b2, W_root2, h2, n_nodes);
  layer_pool_kernel<<<node_blocks, 256, 0, stream>>>(
      h2, rofs, rend, srt, W_rel3, b3, W_root3, batch, sump, maxp, cnt,
      n_nodes);

  // ---- Readout ----
  readout_kernel<<<(GG * LL + 255) / 256, 256, 0, stream>>>(
      sump, maxp, cnt, W_lin, b_lin, out);
}